// Round 11
// baseline (304.491 us; speedup 1.0000x reference)
//
#include <hip/hip_runtime.h>
#include <hip/hip_bf16.h>

// Problem: out = lecac_linear(relu(lecac_linear(x, W1, b1)), W2, b2)
//   x: [262144, 256] f32, W1: [512,256], b1: [512], W2: [256,512], b2: [256]
// R11: R10 skeleton (unfused 2-pass, LDS-staged activations, packed 2-bit
// weight codes in regs) with BM 32->64. R10's k1 was VALU-bound on the weight
// unpack (512 VALU insts vs 64 MFMA per thread-tile, ~109us chip-wide);
// doubling rows/block halves the number of blocks and thus total unpack work
// while doubling MFMA per unpack. Registers stay safe: k1 ~110, k2 ~70.

typedef __attribute__((ext_vector_type(8))) short bf16x8;
typedef __attribute__((ext_vector_type(4))) float f32x4;
typedef __attribute__((ext_vector_type(4))) unsigned short us4;

#define D_IN 256
#define D_HID 512
#define D_OUT 256
#define BM 64

__device__ __forceinline__ unsigned short f2bf(float f) {
  union { __hip_bfloat16 h; unsigned short u; } c;
  c.h = __float2bfloat16(f);
  return c.u;
}

__device__ __forceinline__ bf16x8 cvt8(float4 lo, float4 hi) {
  bf16x8 v;
  v[0] = (short)f2bf(lo.x); v[1] = (short)f2bf(lo.y);
  v[2] = (short)f2bf(lo.z); v[3] = (short)f2bf(lo.w);
  v[4] = (short)f2bf(hi.x); v[5] = (short)f2bf(hi.y);
  v[6] = (short)f2bf(hi.z); v[7] = (short)f2bf(hi.w);
  return v;
}

// DMA 16B per lane: global (per-lane addr) -> LDS (wave-uniform base + lane*16)
__device__ __forceinline__ void gload_lds16(const unsigned short* g, unsigned short* l) {
  __builtin_amdgcn_global_load_lds(
      (const __attribute__((address_space(1))) void*)(const void*)g,
      (__attribute__((address_space(3))) void*)(void*)l, 16, 0, 0);
}

// Unpack 8 codes (half of a 16-code u32, selected by kkl) -> bf16x8.
// Code c (2 bits): 0->0.0, 1->1.0, 2->-2.0, 3->-1.0. (verified R7-R10)
__device__ __forceinline__ bf16x8 unpack8(unsigned w, int kkl) {
  unsigned te = (w >> (4 * kkl)) & 0x03030303u;        // els j = 0,2,4,6
  unsigned to = (w >> (4 * kkl + 2)) & 0x03030303u;    // els j = 1,3,5,7
  int4 o;
  unsigned s;
  s = __builtin_amdgcn_perm(to, te, 0x04040000u) + 0x00040004u;
  o.x = (int)__builtin_amdgcn_perm(0x80008000u, 0xBFC03F00u, s);
  s = __builtin_amdgcn_perm(to, te, 0x05050101u) + 0x00040004u;
  o.y = (int)__builtin_amdgcn_perm(0x80008000u, 0xBFC03F00u, s);
  s = __builtin_amdgcn_perm(to, te, 0x06060202u) + 0x00040004u;
  o.z = (int)__builtin_amdgcn_perm(0x80008000u, 0xBFC03F00u, s);
  s = __builtin_amdgcn_perm(to, te, 0x07070303u) + 0x00040004u;
  o.w = (int)__builtin_amdgcn_perm(0x80008000u, 0xBFC03F00u, s);
  return *(bf16x8*)&o;
}

// ---- prep 1: deterministic f64 partial abs-sums (8 chunks per tensor) ------
__global__ void partial_abs_kernel(const float* __restrict__ W1,
                                   const float* __restrict__ W2,
                                   double* __restrict__ part) {
  const int b = blockIdx.x;                 // 0..15
  const float* W = (b < 8) ? W1 : W2;
  const float* p = W + (b & 7) * 16384;     // 131072 / 8
  double s = 0.0;
  for (int i = threadIdx.x; i < 16384; i += 1024) s += (double)fabsf(p[i]);
  __shared__ double red[1024];
  red[threadIdx.x] = s;
  __syncthreads();
  for (int st = 512; st > 0; st >>= 1) {
    if (threadIdx.x < st) red[threadIdx.x] += red[threadIdx.x + st];
    __syncthreads();
  }
  if (threadIdx.x == 0) part[b] = red[0];
}

// ---- prep 2: pack 2-bit codes in the per-lane fragment order ---------------
// Region 1 (W1, words 0..8191):  word = tt*16 + mf*4 + kp  (mf<4, kp<4)
//   frag row = 64*wv + 16*mf + l15,  k = (2*kp+kkl)*32 + 8*g + j
// Region 2 (W2, words 8192..16383): word = 8192 + tt*16 + mf*8 + kp (mf<2,kp<8)
//   frag row = 32*wv + 16*mf + l15,  k = (2*kp+kkl)*32 + 8*g + j
// Crumb (byte b, crumb c): j = 2b + (c&1), kkl = c>>1.
__global__ void pack_kernel(const float* __restrict__ W1,
                            const float* __restrict__ W2,
                            const double* __restrict__ part,
                            unsigned* __restrict__ pk,
                            float* __restrict__ fscales) {
  int idx = blockIdx.x * 1024 + threadIdx.x;  // 0..16383
  const double* q = part;
  double sA = 1.47 * ((((q[0]+q[1])+(q[2]+q[3]))+((q[4]+q[5])+(q[6]+q[7]))) / 131072.0) + 1e-8;
  double sB = 1.47 * ((((q[8]+q[9])+(q[10]+q[11]))+((q[12]+q[13])+(q[14]+q[15]))) / 131072.0) + 1e-8;
  if (idx == 0) { fscales[0] = (float)sA; fscales[1] = (float)sB; }
  bool is2 = idx >= 8192;
  int r = idx & 8191;
  int tt = r >> 4;                // owner thread 0..511
  int w = r & 15;
  int wv = tt >> 6, lane = tt & 63;
  int l15 = lane & 15, g = (lane >> 4) & 3;
  unsigned word = 0;
  for (int c = 0; c < 4; ++c) {
    for (int b = 0; b < 4; ++b) {
      int j = 2 * b + (c & 1), kkl = c >> 1;
      int code;
      if (!is2) {
        int mf = w >> 2, kp = w & 3;
        int row = 64 * wv + 16 * mf + l15;
        int k = (2 * kp + kkl) * 32 + 8 * g + j;
        double v = rint((double)W1[row * 256 + k] / sA);
        code = (int)fmin(fmax(v, -2.0), 1.0) & 3;
      } else {
        int mf = w >> 3, kp = w & 7;
        int row = 32 * wv + 16 * mf + l15;
        int k = (2 * kp + kkl) * 32 + 8 * g + j;
        double v = rint((double)W2[row * 512 + k] / sB);
        code = (int)fmin(fmax(v, -2.0), 1.0) & 3;
      }
      word |= (unsigned)code << (8 * b + 2 * c);
    }
  }
  pk[idx] = word;
}

// ---------------- K1: h = relu(s1 * (W1q @ x^T) + b1), h bf16 ---------------
// 4096 blocks x 512 threads (8 waves). Block = 64 batch rows. Wave wv owns
// hidden rows [64wv, 64wv+64). x tile reg-staged to LDS as bf16 (32 KB),
// swizzled slot^((row&7)<<2); B-frags = single ds_read_b128 each.
__launch_bounds__(512)
__global__ void k1_gemm(const float* __restrict__ x,
                        const float* __restrict__ b1,
                        const unsigned* __restrict__ pk,
                        const float* __restrict__ fscales,
                        unsigned short* __restrict__ h) {
  __shared__ unsigned short xs[BM * D_IN];   // 64 rows x 256 bf16 = 32 KB
  const int t = threadIdx.x;
  const int lane = t & 63;
  const int wv = t >> 6;
  const int l15 = lane & 15;
  const int g = lane >> 4;
  const long row0 = (long)blockIdx.x * BM;
  const float s1 = fscales[0];
  const f32x4 zero4 = {0.f, 0.f, 0.f, 0.f};

  unsigned w1k[16];
  {
    const uint4* p = (const uint4*)pk + t * 4;
#pragma unroll
    for (int i = 0; i < 4; ++i) {
      uint4 a = p[i];
      w1k[4*i] = a.x; w1k[4*i+1] = a.y; w1k[4*i+2] = a.z; w1k[4*i+3] = a.w;
    }
  }

  // ---- stage x tile: 4096 float4 chunks; thread t covers chunks 2t,2t+1 (+1024j)
  {
    const float4* p = (const float4*)(x + row0 * D_IN);
#pragma unroll
    for (int j = 0; j < 4; ++j) {
      int c0 = j * 1024 + 2 * t;
      int m = c0 >> 6, c4 = c0 & 63;       // c4 even
      float4 v0 = p[c0], v1 = p[c0 + 1];
      bf16x8 e = cvt8(v0, v1);
      int slot = (c4 >> 1) ^ ((m & 7) << 2);
      *(bf16x8*)&xs[m * 256 + slot * 8] = e;
    }
  }
  __syncthreads();

  f32x4 acc[4][4];
#pragma unroll
  for (int a = 0; a < 4; ++a)
#pragma unroll
    for (int b = 0; b < 4; ++b) acc[a][b] = zero4;

#pragma unroll
  for (int kp = 0; kp < 4; ++kp) {
#pragma unroll
    for (int kkl = 0; kkl < 2; ++kkl) {
      int kk = 2 * kp + kkl;
      bf16x8 bx[4];
#pragma unroll
      for (int nf = 0; nf < 4; ++nf) {
        int m = 16 * nf + l15;
        int s = (kk * 4 + g) ^ ((m & 7) << 2);
        bx[nf] = *(const bf16x8*)&xs[m * 256 + s * 8];
      }
#pragma unroll
      for (int mf = 0; mf < 4; ++mf) {
        bf16x8 fr = unpack8(w1k[mf * 4 + kp], kkl);
#pragma unroll
        for (int nf = 0; nf < 4; ++nf)
          acc[mf][nf] = __builtin_amdgcn_mfma_f32_16x16x32_bf16(fr, bx[nf], acc[mf][nf], 0, 0, 0);
      }
    }
  }

  // epilogue: h[m][c] = relu(s1*acc + b1[c]), 8B stores (4 consecutive hidden)
#pragma unroll
  for (int mf = 0; mf < 4; ++mf) {
    int cb = 64 * wv + 16 * mf + 4 * g;
    float4 bb = *(const float4*)&b1[cb];
#pragma unroll
    for (int nf = 0; nf < 4; ++nf) {
      int m = 16 * nf + l15;
      f32x4 a = acc[mf][nf];
      us4 o;
      o.x = f2bf(fmaxf(s1 * a[0] + bb.x, 0.f));
      o.y = f2bf(fmaxf(s1 * a[1] + bb.y, 0.f));
      o.z = f2bf(fmaxf(s1 * a[2] + bb.z, 0.f));
      o.w = f2bf(fmaxf(s1 * a[3] + bb.w, 0.f));
      *(us4*)&h[(row0 + m) * D_HID + cb] = o;
    }
  }
}

// ---------------- K2: out = s2 * (W2q @ h^T) + b2, f32, IN-PLACE over h -----
// 4096 blocks x 512 threads. Block = 64 batch rows. Wave wv owns out cols
// [32wv, 32wv+32). h tile DMA-staged to LDS (64 KB) with source-side swizzle;
// all h-reads happen in the stage, so the post-stage barrier orders them
// before any out store (in-place safe; blocks own disjoint rows).
__launch_bounds__(512)
__global__ void k2_gemm(const unsigned short* __restrict__ h,
                        const float* __restrict__ b2,
                        const unsigned* __restrict__ pk2,
                        const float* __restrict__ fscales,
                        float* __restrict__ out) {
  __shared__ unsigned short hs[BM * D_HID];  // 64 rows x 512 bf16 = 64 KB
  const int t = threadIdx.x;
  const int lane = t & 63;
  const int wv = t >> 6;
  const int l15 = lane & 15;
  const int g = lane >> 4;
  const long row0 = (long)blockIdx.x * BM;
  const float s2 = fscales[1];
  const f32x4 zero4 = {0.f, 0.f, 0.f, 0.f};

  unsigned w2k[16];
  {
    const uint4* p = (const uint4*)pk2 + t * 4;
#pragma unroll
    for (int i = 0; i < 4; ++i) {
      uint4 a = p[i];
      w2k[4*i] = a.x; w2k[4*i+1] = a.y; w2k[4*i+2] = a.z; w2k[4*i+3] = a.w;
    }
  }

  // ---- DMA stage h tile: wave wv stages rows 8wv..8wv+7 (row = 64 chunks of
  // 16B); LDS slot l holds global chunk l ^ ((m&7)<<2)
#pragma unroll
  for (int j = 0; j < 8; ++j) {
    int m = wv * 8 + j;
    gload_lds16(&h[(row0 + m) * D_HID + ((lane ^ ((m & 7) << 2)) & 63) * 8],
                &hs[m * D_HID]);
  }
  asm volatile("s_waitcnt vmcnt(0)" ::: "memory");
  __syncthreads();

  f32x4 acc[2][4];
#pragma unroll
  for (int a = 0; a < 2; ++a)
#pragma unroll
    for (int b = 0; b < 4; ++b) acc[a][b] = zero4;

#pragma unroll
  for (int kp = 0; kp < 8; ++kp) {
#pragma unroll
    for (int kkl = 0; kkl < 2; ++kkl) {
      int kk = 2 * kp + kkl;
      bf16x8 bh[4];
#pragma unroll
      for (int nf = 0; nf < 4; ++nf) {
        int m = 16 * nf + l15;
        int s = (kk * 4 + g) ^ ((m & 7) << 2);
        bh[nf] = *(const bf16x8*)&hs[m * D_HID + s * 8];
      }
#pragma unroll
      for (int mf = 0; mf < 2; ++mf) {
        bf16x8 fr = unpack8(w2k[mf * 8 + kp], kkl);
#pragma unroll
        for (int nf = 0; nf < 4; ++nf)
          acc[mf][nf] = __builtin_amdgcn_mfma_f32_16x16x32_bf16(fr, bh[nf], acc[mf][nf], 0, 0, 0);
      }
    }
  }

#pragma unroll
  for (int mf = 0; mf < 2; ++mf) {
    int n4 = 32 * wv + 16 * mf + 4 * g;
    float4 bb = *(const float4*)&b2[n4];
#pragma unroll
    for (int nf = 0; nf < 4; ++nf) {
      int m = 16 * nf + l15;
      f32x4 a = acc[mf][nf];
      float4 o;
      o.x = s2 * a[0] + bb.x;
      o.y = s2 * a[1] + bb.y;
      o.z = s2 * a[2] + bb.z;
      o.w = s2 * a[3] + bb.w;
      *(float4*)&out[(row0 + m) * D_OUT + n4] = o;
    }
  }
}

extern "C" void kernel_launch(void* const* d_in, const int* in_sizes, int n_in,
                              void* d_out, int out_size, void* d_ws, size_t ws_size,
                              hipStream_t stream) {
  const float* x  = (const float*)d_in[0];
  const float* W1 = (const float*)d_in[1];
  const float* b1 = (const float*)d_in[2];
  const float* W2 = (const float*)d_in[3];
  const float* b2 = (const float*)d_in[4];
  float* out = (float*)d_out;

  // ws layout: [0,128) f64 partials, [128,136) f32 scales, pk at 1024 (64 KB)
  double* part = (double*)d_ws;
  float* fsc = (float*)((char*)d_ws + 128);
  unsigned* pk = (unsigned*)((char*)d_ws + 1024);

  // h (262144 x 512 bf16 = 268 MB) lives in d_out (262144 x 256 f32 = 268 MB)
  unsigned short* hbuf = (unsigned short*)d_out;

  int Brows = in_sizes[0] / D_IN;     // 262144
  int nblk = Brows / BM;              // 4096

  partial_abs_kernel<<<dim3(16), dim3(1024), 0, stream>>>(W1, W2, part);
  pack_kernel<<<dim3(16), dim3(1024), 0, stream>>>(W1, W2, part, pk, fsc);
  k1_gemm<<<dim3(nblk), dim3(512), 0, stream>>>(x, b1, pk, fsc, hbuf);
  k2_gemm<<<dim3(nblk), dim3(512), 0, stream>>>(hbuf, b2, pk + 8192, fsc, out);
}